// Round 11
// baseline (161.903 us; speedup 1.0000x reference)
//
#include <hip/hip_runtime.h>
#include <math.h>

#pragma clang fp contract(off)

#define N_ROIS     1500
#define NUM_CLS    81
#define FG         80
#define MAXC       1536      // per-class candidate capacity (worst case N_ROIS)
#define NMS_T      0.5f
#define SCORE_T    0.05f
#define MAX_DET    100
#define TOTAL      (FG * N_ROIS)
#define TPB        256
#define K1_BLOCKS  256
#define K2_TPB     1024
#define NCHUNK     ((N_ROIS + TPB - 1) / TPB)   // 6
#define SEGW       1500      // per-class kept-segment stride (max possible)
#define DENSECAP   8192      // K2 dense LDS capacity for kept scores

// float <-> order-preserving uint
__device__ __forceinline__ unsigned f2s(float f) {
    unsigned u = __float_as_uint(f);
    return (u & 0x80000000u) ? ~u : (u | 0x80000000u);
}
__device__ __forceinline__ float s2f(unsigned u) {
    return __uint_as_float((u & 0x80000000u) ? (u & 0x7FFFFFFFu) : ~u);
}

// ---------------- K1 (256 blocks, plain launch, NO in-kernel device sync) --
// blocks 0..79:  per-class NMS — wave-ballot compaction of valid (s > 0.05)
//   -> rank-by-counting sort (keys unique: score desc, idx asc => exact
//   stable order) -> decode valid boxes -> bitmask NMS (MxM bit-matrix via
//   __ballot + register-only scan on wave 0; iterative fallback if matrix
//   exceeds LDS) -> write kept entries into per-class segment b*SEGW and a
//   plain kcnt[b] (no global atomics, no memset node needed: every class
//   block writes its count every launch, so ws poison never survives).
// blocks 80..255: fill out (dets=0, cls_idx=r/1500+1, keep=0) — disjoint.
// Kernel boundary provides the device-scope release (R9 lesson: grid.sync
// costs ~25 us on 8-XCD MI355X; R10 lesson: each graph node ~2.3 us).
__global__ __launch_bounds__(TPB) void nms_k1(
    const float* __restrict__ rois,    // (N,5)
    const float* __restrict__ deltas,  // (N, 4*81)
    const float* __restrict__ prob,    // (N, 81)
    const float* __restrict__ iminfo,  // (1,3)
    float4* __restrict__ keptBox,      // (FG*SEGW)
    int*    __restrict__ keptRow,      // (FG*SEGW)
    float*  __restrict__ keptScore,    // (FG*SEGW)
    int*    __restrict__ kcnt,         // (FG) plain per-class counts
    float*  __restrict__ out)
{
    const int tid  = threadIdx.x;
    const int lane = tid & 63;
    const int wv   = tid >> 6;
    const int b    = blockIdx.x;

    if (b >= FG) {
        // ---- fill blocks: dets=0, cls_idx, keep=0 (float4, grid-stride) ----
        const float4 z4 = make_float4(0.f, 0.f, 0.f, 0.f);
        const int stride = (K1_BLOCKS - FG) * TPB;
        int g = (b - FG) * TPB + tid;

        float4* dets4 = (float4*)out;                       // 180000
        for (int i = g; i < TOTAL * 6 / 4; i += stride) dets4[i] = z4;

        float4* cls4  = (float4*)(out + (size_t)TOTAL * 6); // 30000
        float4* keep4 = (float4*)(out + (size_t)TOTAL * 7);
        for (int i = g; i < TOTAL / 4; i += stride) {
            float fc = (float)((i * 4) / N_ROIS + 1);       // 1500%4==0
            cls4[i]  = make_float4(fc, fc, fc, fc);
            keep4[i] = z4;
        }
        return;
    }

    __shared__ unsigned long long key[MAXC];   // keys; later the mask matrix
    __shared__ unsigned long long skey[MAXC];  // rank-sorted keys
    __shared__ float4 box4[MAXC];
    __shared__ float  areaA[MAXC];
    __shared__ unsigned char keepf[MAXC], supp[MAXC];
    __shared__ int mcnt, kloc;

    const int c = b + 1;              // class 1..80
    const int cbase = b * N_ROIS;

    if (tid == 0) { mcnt = 0; kloc = 0; }
    __syncthreads();

    // --- compaction: batch-load prob column, then wave-ballot compact ---
    float sv[NCHUNK];
    #pragma unroll
    for (int t = 0; t < NCHUNK; ++t) {
        int i = t * TPB + tid;
        sv[t] = (i < N_ROIS) ? prob[i * NUM_CLS + c] : 0.0f;
    }
    #pragma unroll
    for (int t = 0; t < NCHUNK; ++t) {
        int i = t * TPB + tid;
        bool val = (i < N_ROIS) && (sv[t] > SCORE_T);
        unsigned long long m = __ballot(val);
        int base = 0;
        if (lane == 0 && m) base = atomicAdd(&mcnt, __popcll(m));
        base = __shfl(base, 0, 64);
        if (val) {
            int pos = base + __popcll(m & ((1ull << lane) - 1ull));
            key[pos] = ((unsigned long long)(~f2s(sv[t])) << 32) | (unsigned)i;
        }
    }
    __syncthreads();
    const int M = mcnt;
    if (M == 0) {
        if (tid == 0) kcnt[b] = 0;
        return;
    }

    // --- rank-by-counting sort: keys unique -> ranks are a permutation ---
    for (int i = tid; i < M; i += TPB) {
        unsigned long long kk = key[i];
        int cnt = 0;
        #pragma unroll 4
        for (int j = 0; j < M; ++j) cnt += (int)(key[j] < kk);
        skey[cnt] = kk;
    }
    __syncthreads();

    // --- decode boxes at sorted positions (match numpy op-for-op) ---
    const float Hm1 = iminfo[0] - 1.0f;
    const float Wm1 = iminfo[1] - 1.0f;
    for (int k = tid; k < M; k += TPB) {
        unsigned long long kk = skey[k];
        int i = (int)(kk & 0xFFFFFFFFu);
        const float* rp = rois + i * 5;
        float x1 = rp[1], y1 = rp[2], x2 = rp[3], y2 = rp[4];
        float w  = x2 - x1 + 1.0f;
        float h  = y2 - y1 + 1.0f;
        float cx = x1 + 0.5f * w;
        float cy = y1 + 0.5f * h;
        const float* dp = deltas + i * (4 * NUM_CLS) + c * 4;
        float dx = dp[0] / 10.0f, dy = dp[1] / 10.0f;
        float dw = dp[2] / 5.0f,  dh = dp[3] / 5.0f;
        float pcx = cx + w * dx;
        float pcy = cy + h * dy;
        float pw  = w * expf(dw);
        float ph  = h * expf(dh);
        float a1 = pcx - 0.5f * pw;
        float a2 = pcy - 0.5f * ph;
        float a3 = pcx + 0.5f * pw - 1.0f;
        float a4 = pcy + 0.5f * ph - 1.0f;
        a1 = fminf(fmaxf(a1, 0.0f), Wm1);
        a2 = fminf(fmaxf(a2, 0.0f), Hm1);
        a3 = fminf(fmaxf(a3, 0.0f), Wm1);
        a4 = fminf(fmaxf(a4, 0.0f), Hm1);
        box4[k]  = make_float4(a1, a2, a3, a4);
        areaA[k] = (a3 - a1 + 1.0f) * (a4 - a2 + 1.0f);
        keepf[k] = 0; supp[k] = 0;
    }
    __syncthreads();

    const int MW = (M + 63) >> 6;          // 64-bit words per mask row
    const bool fast = (M * MW <= MAXC);    // mask matrix fits in key[]

    if (fast) {
        // --- suppression bit-matrix: row r, bit j iff j>r && iou>0.5.
        //     Words w < r>>6 are identically zero: store 0, skip IoU. ---
        for (int r = wv; r < M; r += TPB / 64) {
            float4 br = box4[r];
            float  ar = areaA[r];
            const int w0 = r >> 6;
            if (lane == 0)
                for (int w = 0; w < w0; ++w) key[r * MW + w] = 0ull;
            for (int w = w0; w < MW; ++w) {
                int col = (w << 6) | lane;
                bool inb = (col < M);
                int j = inb ? col : 0;
                float4 bj = box4[j];
                float  aj = areaA[j];
                float iw = fminf(br.z, bj.z) - fmaxf(br.x, bj.x) + 1.0f;
                float ih = fminf(br.w, bj.w) - fmaxf(br.y, bj.y) + 1.0f;
                iw = fmaxf(iw, 0.0f);
                ih = fmaxf(ih, 0.0f);
                float inter = iw * ih;
                float iou = inter / ((ar + aj) - inter);
                bool pred = inb && (col > r) && (iou > NMS_T);
                unsigned long long mk = __ballot(pred);
                if (lane == 0) key[r * MW + w] = mk;
            }
        }
        __syncthreads();

        // --- serial scan, wave 0, prefetched register-only chain ---
        if (tid < 64) {
            const int lw = (tid < MW) ? tid : 0;
            unsigned long long acc = 0;        // suppressed bits, word `tid`
            unsigned long long mcur = key[lw]; // row 0
            for (int k = 0; k < M; ++k) {
                unsigned long long mnext =
                    (k + 1 < M) ? key[(k + 1) * MW + lw] : 0ull;
                int bit = (int)((acc >> (k & 63)) & 1ull);
                int sup = __shfl(bit, k >> 6, 64);
                if (!sup) {                    // wave-uniform branch
                    acc |= mcur;
                    if (tid == 0) keepf[k] = 1;
                }
                mcur = mnext;
            }
        }
        __syncthreads();
    } else {
        // --- fallback: iterative greedy NMS (correct for any M) ---
        for (int k = 0; k < M; ++k) {
            if (!supp[k]) {
                if (tid == 0) keepf[k] = 1;
                float4 bk = box4[k];
                float  ak = areaA[k];
                for (int j = k + 1 + tid; j < M; j += TPB) {
                    float4 bj = box4[j];
                    float  aj = areaA[j];
                    float iw = fminf(bk.z, bj.z) - fmaxf(bk.x, bj.x) + 1.0f;
                    float ih = fminf(bk.w, bj.w) - fmaxf(bk.y, bj.y) + 1.0f;
                    iw = fmaxf(iw, 0.0f);
                    ih = fmaxf(ih, 0.0f);
                    float inter = iw * ih;
                    float iou = inter / ((ak + aj) - inter);
                    if (iou > NMS_T) supp[j] = 1;
                }
            }
            __syncthreads();
        }
    }

    // --- write kept entries into this class's segment (local LDS counter) ---
    const int segb = b * SEGW;
    for (int k = tid; k < M; k += TPB) {
        if (keepf[k]) {
            int p = atomicAdd(&kloc, 1);
            keptRow[segb + p]   = cbase + k;
            keptBox[segb + p]   = box4[k];
            keptScore[segb + p] = s2f(~(unsigned)(skey[k] >> 32));
        }
    }
    __syncthreads();
    if (tid == 0) kcnt[b] = kloc;
}

// ---------------- K2 (1 block x 1024 threads): kth select + patch ----------
// Sum the 80 per-class counts; compact all kept scores into dense LDS once;
// exact 100th-largest via 4 MSB-first radix-256 passes over LDS (per-group
// privatized histograms, parallel suffix-scan digit pick; tie-exact;
// global segment-walk fallback if n > DENSECAP). Then the SAME block
// patches kept rows with s >= kth.
__global__ __launch_bounds__(K2_TPB) void kth_patch_k2(
    const int*    __restrict__ kcnt,
    const int*    __restrict__ keptRow,
    const float4* __restrict__ keptBox,
    const float*  __restrict__ keptScore,
    float* __restrict__ out)
{
    __shared__ int cnts[FG];
    __shared__ int offs[FG + 1];
    __shared__ int hist4[4][256];
    __shared__ unsigned sbits[DENSECAP];   // 32 KB
    __shared__ int wtot[4];
    __shared__ unsigned s_pref;
    __shared__ int s_kk;
    __shared__ float s_kth;

    const int tid  = threadIdx.x;
    const int lane = tid & 63;
    const int wv   = tid >> 6;        // 0..15
    const int hp   = wv & 3;          // histogram copy

    // --- counts + exclusive offsets (80 independent LDS reads, reg chain) ---
    if (tid < FG) cnts[tid] = kcnt[tid];
    __syncthreads();
    if (tid == 0) {
        int acc = 0;
        #pragma unroll 8
        for (int b2 = 0; b2 < FG; ++b2) { offs[b2] = acc; acc += cnts[b2]; }
        offs[FG] = acc;
    }
    __syncthreads();
    const int n = offs[FG];

    if (n > MAX_DET) {
        const bool dense = (n <= DENSECAP);
        if (dense) {
            // compact all kept scores into LDS (segment walk)
            for (int b2 = 0; b2 < FG; ++b2) {
                const int cb = cnts[b2], ob = offs[b2], gb = b2 * SEGW;
                for (int i = tid; i < cb; i += K2_TPB)
                    sbits[ob + i] = f2s(keptScore[gb + i]);
            }
        }
        if (tid == 0) { s_pref = 0u; s_kk = MAX_DET; }
        __syncthreads();

        for (int d = 0; d < 4; ++d) {
            const int shift = 24 - 8 * d;        // 24,16,8,0
            if (tid < 256) {
                #pragma unroll
                for (int w = 0; w < 4; ++w) hist4[w][tid] = 0;
            }
            __syncthreads();
            const unsigned pref = s_pref;
            if (dense) {
                for (int i = tid; i < n; i += K2_TPB) {
                    unsigned u = sbits[i];
                    if (d == 0 || (u >> (shift + 8)) == pref)
                        atomicAdd(&hist4[hp][(u >> shift) & 255u], 1);
                }
            } else {
                for (int b2 = 0; b2 < FG; ++b2) {
                    const int cb = cnts[b2], gb = b2 * SEGW;
                    for (int i = tid; i < cb; i += K2_TPB) {
                        unsigned u = f2s(keptScore[gb + i]);
                        if (d == 0 || (u >> (shift + 8)) == pref)
                            atomicAdd(&hist4[hp][(u >> shift) & 255u], 1);
                    }
                }
            }
            __syncthreads();
            // digit pick: threads 0..255 own one bin (waves 0..3),
            // wave suffix-scan + cross-wave totals -> S_ge/S_gt per bin
            if (tid < 256) {
                const int h = hist4[0][tid] + hist4[1][tid] +
                              hist4[2][tid] + hist4[3][tid];
                int r = h;
                #pragma unroll
                for (int off = 1; off < 64; off <<= 1) {
                    int o = __shfl_down(r, off, 64);
                    if (lane + off < 64) r += o;
                }
                if (lane == 0) wtot[wv] = r;
            }
            __syncthreads();
            if (tid < 256) {
                const int h = hist4[0][tid] + hist4[1][tid] +
                              hist4[2][tid] + hist4[3][tid];
                int r = h;
                #pragma unroll
                for (int off = 1; off < 64; off <<= 1) {
                    int o = __shfl_down(r, off, 64);
                    if (lane + off < 64) r += o;
                }
                int hi = 0;
                #pragma unroll
                for (int w2 = 0; w2 < 4; ++w2) if (w2 > wv) hi += wtot[w2];
                const int S_ge = r + hi, S_gt = S_ge - h;
                const int kk = s_kk;
                if (S_gt < kk && S_ge >= kk) {            // exactly one thread
                    s_pref = (pref << 8) | (unsigned)tid;
                    s_kk   = kk - S_gt;
                }
            }
            __syncthreads();
        }
        if (tid == 0) s_kth = s2f(s_pref);
    } else {
        if (tid == 0) s_kth = -INFINITY;
    }
    __syncthreads();
    const float kth = s_kth;

    // --- patch kept rows (segment walk, fire-and-forget stores) ---
    for (int b2 = 0; b2 < FG; ++b2) {
        const int cb = cnts[b2], gb = b2 * SEGW;
        for (int i = tid; i < cb; i += K2_TPB) {
            float s = keptScore[gb + i];
            if (s >= kth) {
                int r = keptRow[gb + i];
                float4 b4 = keptBox[gb + i];
                float* dst = out + (size_t)r * 6;
                dst[1] = b4.x; dst[2] = b4.y; dst[3] = b4.z;
                dst[4] = b4.w; dst[5] = s;
                out[(size_t)TOTAL * 7 + r] = 1.0f;
            }
        }
    }
}

extern "C" void kernel_launch(void* const* d_in, const int* in_sizes, int n_in,
                              void* d_out, int out_size, void* d_ws, size_t ws_size,
                              hipStream_t stream) {
    const float* rois   = (const float*)d_in[0];  // (1500,5)
    const float* deltas = (const float*)d_in[1];  // (1500,324)
    const float* prob   = (const float*)d_in[2];  // (1500,81)
    const float* iminfo = (const float*)d_in[3];  // (1,3)
    float* out = (float*)d_out;

    // workspace: float4 first for 16B alignment
    float4* keptBox   = (float4*)d_ws;                     // FG*SEGW
    int*    keptRow   = (int*)(keptBox + FG * SEGW);       // FG*SEGW
    float*  keptScore = (float*)(keptRow + FG * SEGW);     // FG*SEGW
    int*    kcnt      = (int*)(keptScore + FG * SEGW);     // FG

    nms_k1<<<K1_BLOCKS, TPB, 0, stream>>>(rois, deltas, prob, iminfo,
                                          keptBox, keptRow, keptScore, kcnt, out);
    kth_patch_k2<<<1, K2_TPB, 0, stream>>>(kcnt, keptRow, keptBox, keptScore, out);
}

// Round 12
// 107.293 us; speedup vs baseline: 1.5090x; 1.5090x over previous
//
#include <hip/hip_runtime.h>
#include <math.h>

#pragma clang fp contract(off)

#define N_ROIS     1500
#define NUM_CLS    81
#define FG         80
#define MAXC       1536      // per-class candidate capacity (worst case N_ROIS)
#define NMS_T      0.5f
#define SCORE_T    0.05f
#define MAX_DET    100
#define TOTAL      (FG * N_ROIS)
#define TPB        256
#define K1_BLOCKS  256
#define K2_TPB     1024
#define NWAVES     (K2_TPB / 64)                // 16
#define NCHUNK     ((N_ROIS + TPB - 1) / TPB)   // 6
#define SEGW       1500      // per-class kept-segment stride (max possible)
#define DENSECAP   8192      // K2 dense LDS capacity for kept scores

// float <-> order-preserving uint
__device__ __forceinline__ unsigned f2s(float f) {
    unsigned u = __float_as_uint(f);
    return (u & 0x80000000u) ? ~u : (u | 0x80000000u);
}
__device__ __forceinline__ float s2f(unsigned u) {
    return __uint_as_float((u & 0x80000000u) ? (u & 0x7FFFFFFFu) : ~u);
}

// ---------------- K1 (256 blocks, plain launch, NO in-kernel device sync) --
// blocks 0..79:  per-class NMS — wave-ballot compaction of valid (s > 0.05)
//   -> rank-by-counting sort (keys unique: score desc, idx asc => exact
//   stable order) -> decode valid boxes -> bitmask NMS (MxM bit-matrix via
//   __ballot + register-only scan on wave 0; iterative fallback if matrix
//   exceeds LDS) -> write kept entries into per-class segment b*SEGW and a
//   plain kcnt[b] (no global atomics, no memset node: every class block
//   writes its count every launch, so ws poison never survives).
// blocks 80..255: fill out (dets=0, cls_idx=r/1500+1, keep=0) — disjoint.
// R9 lesson: grid.sync ~25 us on 8-XCD MI355X. R10: each graph node ~2.3 us.
// R11 lesson: segmented storage needs a SEGMENT-PARALLEL reader (see K2).
__global__ __launch_bounds__(TPB) void nms_k1(
    const float* __restrict__ rois,    // (N,5)
    const float* __restrict__ deltas,  // (N, 4*81)
    const float* __restrict__ prob,    // (N, 81)
    const float* __restrict__ iminfo,  // (1,3)
    float4* __restrict__ keptBox,      // (FG*SEGW)
    int*    __restrict__ keptRow,      // (FG*SEGW)
    float*  __restrict__ keptScore,    // (FG*SEGW)
    int*    __restrict__ kcnt,         // (FG) plain per-class counts
    float*  __restrict__ out)
{
    const int tid  = threadIdx.x;
    const int lane = tid & 63;
    const int wv   = tid >> 6;
    const int b    = blockIdx.x;

    if (b >= FG) {
        // ---- fill blocks: dets=0, cls_idx, keep=0 (float4, grid-stride) ----
        const float4 z4 = make_float4(0.f, 0.f, 0.f, 0.f);
        const int stride = (K1_BLOCKS - FG) * TPB;
        int g = (b - FG) * TPB + tid;

        float4* dets4 = (float4*)out;                       // 180000
        for (int i = g; i < TOTAL * 6 / 4; i += stride) dets4[i] = z4;

        float4* cls4  = (float4*)(out + (size_t)TOTAL * 6); // 30000
        float4* keep4 = (float4*)(out + (size_t)TOTAL * 7);
        for (int i = g; i < TOTAL / 4; i += stride) {
            float fc = (float)((i * 4) / N_ROIS + 1);       // 1500%4==0
            cls4[i]  = make_float4(fc, fc, fc, fc);
            keep4[i] = z4;
        }
        return;
    }

    __shared__ unsigned long long key[MAXC];   // keys; later the mask matrix
    __shared__ unsigned long long skey[MAXC];  // rank-sorted keys
    __shared__ float4 box4[MAXC];
    __shared__ float  areaA[MAXC];
    __shared__ unsigned char keepf[MAXC], supp[MAXC];
    __shared__ int mcnt, kloc;

    const int c = b + 1;              // class 1..80
    const int cbase = b * N_ROIS;

    if (tid == 0) { mcnt = 0; kloc = 0; }
    __syncthreads();

    // --- compaction: batch-load prob column, then wave-ballot compact ---
    float sv[NCHUNK];
    #pragma unroll
    for (int t = 0; t < NCHUNK; ++t) {
        int i = t * TPB + tid;
        sv[t] = (i < N_ROIS) ? prob[i * NUM_CLS + c] : 0.0f;
    }
    #pragma unroll
    for (int t = 0; t < NCHUNK; ++t) {
        int i = t * TPB + tid;
        bool val = (i < N_ROIS) && (sv[t] > SCORE_T);
        unsigned long long m = __ballot(val);
        int base = 0;
        if (lane == 0 && m) base = atomicAdd(&mcnt, __popcll(m));
        base = __shfl(base, 0, 64);
        if (val) {
            int pos = base + __popcll(m & ((1ull << lane) - 1ull));
            key[pos] = ((unsigned long long)(~f2s(sv[t])) << 32) | (unsigned)i;
        }
    }
    __syncthreads();
    const int M = mcnt;
    if (M == 0) {
        if (tid == 0) kcnt[b] = 0;
        return;
    }

    // --- rank-by-counting sort: keys unique -> ranks are a permutation ---
    for (int i = tid; i < M; i += TPB) {
        unsigned long long kk = key[i];
        int cnt = 0;
        #pragma unroll 4
        for (int j = 0; j < M; ++j) cnt += (int)(key[j] < kk);
        skey[cnt] = kk;
    }
    __syncthreads();

    // --- decode boxes at sorted positions (match numpy op-for-op) ---
    const float Hm1 = iminfo[0] - 1.0f;
    const float Wm1 = iminfo[1] - 1.0f;
    for (int k = tid; k < M; k += TPB) {
        unsigned long long kk = skey[k];
        int i = (int)(kk & 0xFFFFFFFFu);
        const float* rp = rois + i * 5;
        float x1 = rp[1], y1 = rp[2], x2 = rp[3], y2 = rp[4];
        float w  = x2 - x1 + 1.0f;
        float h  = y2 - y1 + 1.0f;
        float cx = x1 + 0.5f * w;
        float cy = y1 + 0.5f * h;
        const float* dp = deltas + i * (4 * NUM_CLS) + c * 4;
        float dx = dp[0] / 10.0f, dy = dp[1] / 10.0f;
        float dw = dp[2] / 5.0f,  dh = dp[3] / 5.0f;
        float pcx = cx + w * dx;
        float pcy = cy + h * dy;
        float pw  = w * expf(dw);
        float ph  = h * expf(dh);
        float a1 = pcx - 0.5f * pw;
        float a2 = pcy - 0.5f * ph;
        float a3 = pcx + 0.5f * pw - 1.0f;
        float a4 = pcy + 0.5f * ph - 1.0f;
        a1 = fminf(fmaxf(a1, 0.0f), Wm1);
        a2 = fminf(fmaxf(a2, 0.0f), Hm1);
        a3 = fminf(fmaxf(a3, 0.0f), Wm1);
        a4 = fminf(fmaxf(a4, 0.0f), Hm1);
        box4[k]  = make_float4(a1, a2, a3, a4);
        areaA[k] = (a3 - a1 + 1.0f) * (a4 - a2 + 1.0f);
        keepf[k] = 0; supp[k] = 0;
    }
    __syncthreads();

    const int MW = (M + 63) >> 6;          // 64-bit words per mask row
    const bool fast = (M * MW <= MAXC);    // mask matrix fits in key[]

    if (fast) {
        // --- suppression bit-matrix: row r, bit j iff j>r && iou>0.5.
        //     Words w < r>>6 are identically zero: store 0, skip IoU. ---
        for (int r = wv; r < M; r += TPB / 64) {
            float4 br = box4[r];
            float  ar = areaA[r];
            const int w0 = r >> 6;
            if (lane == 0)
                for (int w = 0; w < w0; ++w) key[r * MW + w] = 0ull;
            for (int w = w0; w < MW; ++w) {
                int col = (w << 6) | lane;
                bool inb = (col < M);
                int j = inb ? col : 0;
                float4 bj = box4[j];
                float  aj = areaA[j];
                float iw = fminf(br.z, bj.z) - fmaxf(br.x, bj.x) + 1.0f;
                float ih = fminf(br.w, bj.w) - fmaxf(br.y, bj.y) + 1.0f;
                iw = fmaxf(iw, 0.0f);
                ih = fmaxf(ih, 0.0f);
                float inter = iw * ih;
                float iou = inter / ((ar + aj) - inter);
                bool pred = inb && (col > r) && (iou > NMS_T);
                unsigned long long mk = __ballot(pred);
                if (lane == 0) key[r * MW + w] = mk;
            }
        }
        __syncthreads();

        // --- serial scan, wave 0, prefetched register-only chain ---
        if (tid < 64) {
            const int lw = (tid < MW) ? tid : 0;
            unsigned long long acc = 0;        // suppressed bits, word `tid`
            unsigned long long mcur = key[lw]; // row 0
            for (int k = 0; k < M; ++k) {
                unsigned long long mnext =
                    (k + 1 < M) ? key[(k + 1) * MW + lw] : 0ull;
                int bit = (int)((acc >> (k & 63)) & 1ull);
                int sup = __shfl(bit, k >> 6, 64);
                if (!sup) {                    // wave-uniform branch
                    acc |= mcur;
                    if (tid == 0) keepf[k] = 1;
                }
                mcur = mnext;
            }
        }
        __syncthreads();
    } else {
        // --- fallback: iterative greedy NMS (correct for any M) ---
        for (int k = 0; k < M; ++k) {
            if (!supp[k]) {
                if (tid == 0) keepf[k] = 1;
                float4 bk = box4[k];
                float  ak = areaA[k];
                for (int j = k + 1 + tid; j < M; j += TPB) {
                    float4 bj = box4[j];
                    float  aj = areaA[j];
                    float iw = fminf(bk.z, bj.z) - fmaxf(bk.x, bj.x) + 1.0f;
                    float ih = fminf(bk.w, bj.w) - fmaxf(bk.y, bj.y) + 1.0f;
                    iw = fmaxf(iw, 0.0f);
                    ih = fmaxf(ih, 0.0f);
                    float inter = iw * ih;
                    float iou = inter / ((ak + aj) - inter);
                    if (iou > NMS_T) supp[j] = 1;
                }
            }
            __syncthreads();
        }
    }

    // --- write kept entries into this class's segment (local LDS counter) ---
    const int segb = b * SEGW;
    for (int k = tid; k < M; k += TPB) {
        if (keepf[k]) {
            int p = atomicAdd(&kloc, 1);
            keptRow[segb + p]   = cbase + k;
            keptBox[segb + p]   = box4[k];
            keptScore[segb + p] = s2f(~(unsigned)(skey[k] >> 32));
        }
    }
    __syncthreads();
    if (tid == 0) kcnt[b] = kloc;
}

// ---------------- K2 (1 block x 1024 threads): kth select + patch ----------
// ALL segment walks are wave-parallel (wave wv owns segments wv, wv+16, ...;
// 64 lanes cover a segment's ~60 entries in one iteration) — R11's
// sequential 80-segment walk was 80 exposed latencies (~25 us per walk).
// Offsets computed by 80 threads in parallel (independent prefix sums).
// Exact 100th-largest via 4 MSB-first radix-256 passes over a dense LDS
// copy (per-group privatized histograms, suffix-scan digit pick; tie-exact;
// wave-parallel global-walk fallback if n > DENSECAP). Then the same block
// patches kept rows with s >= kth.
__global__ __launch_bounds__(K2_TPB) void kth_patch_k2(
    const int*    __restrict__ kcnt,
    const int*    __restrict__ keptRow,
    const float4* __restrict__ keptBox,
    const float*  __restrict__ keptScore,
    float* __restrict__ out)
{
    __shared__ int cnts[FG];
    __shared__ int offs[FG];
    __shared__ int hist4[4][256];
    __shared__ unsigned sbits[DENSECAP];   // 32 KB
    __shared__ int wtot[4];
    __shared__ unsigned s_pref;
    __shared__ int s_kk;
    __shared__ float s_kth;

    const int tid  = threadIdx.x;
    const int lane = tid & 63;
    const int wv   = tid >> 6;        // 0..15
    const int hp   = wv & 3;          // histogram copy

    // --- counts + PARALLEL exclusive offsets (threads 0..79 independent) ---
    if (tid < FG) cnts[tid] = kcnt[tid];
    __syncthreads();
    if (tid < FG) {
        int a = 0;
        for (int j = 0; j < FG; ++j) a += (j < tid) ? cnts[j] : 0;
        offs[tid] = a;
    }
    __syncthreads();
    const int n = offs[FG - 1] + cnts[FG - 1];

    if (n > MAX_DET) {
        const bool dense = (n <= DENSECAP);
        if (dense) {
            // compact all kept scores into LDS — wave-parallel segment walk
            for (int b2 = wv; b2 < FG; b2 += NWAVES) {
                const int cb = cnts[b2], ob = offs[b2], gb = b2 * SEGW;
                for (int i = lane; i < cb; i += 64)
                    sbits[ob + i] = f2s(keptScore[gb + i]);
            }
        }
        if (tid == 0) { s_pref = 0u; s_kk = MAX_DET; }
        __syncthreads();

        for (int d = 0; d < 4; ++d) {
            const int shift = 24 - 8 * d;        // 24,16,8,0
            if (tid < 256) {
                #pragma unroll
                for (int w = 0; w < 4; ++w) hist4[w][tid] = 0;
            }
            __syncthreads();
            const unsigned pref = s_pref;
            if (dense) {
                for (int i = tid; i < n; i += K2_TPB) {
                    unsigned u = sbits[i];
                    if (d == 0 || (u >> (shift + 8)) == pref)
                        atomicAdd(&hist4[hp][(u >> shift) & 255u], 1);
                }
            } else {
                for (int b2 = wv; b2 < FG; b2 += NWAVES) {   // wave-parallel
                    const int cb = cnts[b2], gb = b2 * SEGW;
                    for (int i = lane; i < cb; i += 64) {
                        unsigned u = f2s(keptScore[gb + i]);
                        if (d == 0 || (u >> (shift + 8)) == pref)
                            atomicAdd(&hist4[hp][(u >> shift) & 255u], 1);
                    }
                }
            }
            __syncthreads();
            // digit pick: threads 0..255 own one bin (waves 0..3),
            // wave suffix-scan + cross-wave totals -> S_ge/S_gt per bin
            if (tid < 256) {
                const int h = hist4[0][tid] + hist4[1][tid] +
                              hist4[2][tid] + hist4[3][tid];
                int r = h;
                #pragma unroll
                for (int off = 1; off < 64; off <<= 1) {
                    int o = __shfl_down(r, off, 64);
                    if (lane + off < 64) r += o;
                }
                if (lane == 0) wtot[wv] = r;
            }
            __syncthreads();
            if (tid < 256) {
                const int h = hist4[0][tid] + hist4[1][tid] +
                              hist4[2][tid] + hist4[3][tid];
                int r = h;
                #pragma unroll
                for (int off = 1; off < 64; off <<= 1) {
                    int o = __shfl_down(r, off, 64);
                    if (lane + off < 64) r += o;
                }
                int hi = 0;
                #pragma unroll
                for (int w2 = 0; w2 < 4; ++w2) if (w2 > wv) hi += wtot[w2];
                const int S_ge = r + hi, S_gt = S_ge - h;
                const int kk = s_kk;
                if (S_gt < kk && S_ge >= kk) {            // exactly one thread
                    s_pref = (pref << 8) | (unsigned)tid;
                    s_kk   = kk - S_gt;
                }
            }
            __syncthreads();
        }
        if (tid == 0) s_kth = s2f(s_pref);
    } else {
        if (tid == 0) s_kth = -INFINITY;
    }
    __syncthreads();
    const float kth = s_kth;

    // --- patch kept rows — wave-parallel segment walk ---
    for (int b2 = wv; b2 < FG; b2 += NWAVES) {
        const int cb = cnts[b2], gb = b2 * SEGW;
        for (int i = lane; i < cb; i += 64) {
            float s = keptScore[gb + i];
            if (s >= kth) {
                int r = keptRow[gb + i];
                float4 b4 = keptBox[gb + i];
                float* dst = out + (size_t)r * 6;
                dst[1] = b4.x; dst[2] = b4.y; dst[3] = b4.z;
                dst[4] = b4.w; dst[5] = s;
                out[(size_t)TOTAL * 7 + r] = 1.0f;
            }
        }
    }
}

extern "C" void kernel_launch(void* const* d_in, const int* in_sizes, int n_in,
                              void* d_out, int out_size, void* d_ws, size_t ws_size,
                              hipStream_t stream) {
    const float* rois   = (const float*)d_in[0];  // (1500,5)
    const float* deltas = (const float*)d_in[1];  // (1500,324)
    const float* prob   = (const float*)d_in[2];  // (1500,81)
    const float* iminfo = (const float*)d_in[3];  // (1,3)
    float* out = (float*)d_out;

    // workspace: float4 first for 16B alignment
    float4* keptBox   = (float4*)d_ws;                     // FG*SEGW
    int*    keptRow   = (int*)(keptBox + FG * SEGW);       // FG*SEGW
    float*  keptScore = (float*)(keptRow + FG * SEGW);     // FG*SEGW
    int*    kcnt      = (int*)(keptScore + FG * SEGW);     // FG

    nms_k1<<<K1_BLOCKS, TPB, 0, stream>>>(rois, deltas, prob, iminfo,
                                          keptBox, keptRow, keptScore, kcnt, out);
    kth_patch_k2<<<1, K2_TPB, 0, stream>>>(kcnt, keptRow, keptBox, keptScore, out);
}

// Round 13
// 103.816 us; speedup vs baseline: 1.5595x; 1.0335x over previous
//
#include <hip/hip_runtime.h>
#include <math.h>

#pragma clang fp contract(off)

#define N_ROIS     1500
#define NUM_CLS    81
#define FG         80
#define MAXC       1536      // per-class candidate capacity (worst case N_ROIS)
#define NMS_T      0.5f
#define SCORE_T    0.05f
#define MAX_DET    100
#define TOTAL      (FG * N_ROIS)
#define TPB        256
#define K1_BLOCKS  256
#define K2_TPB     1024
#define NCHUNK     ((N_ROIS + TPB - 1) / TPB)   // 6
#define SUBCAP     8192      // kth LDS subset capacity

// float <-> order-preserving uint
__device__ __forceinline__ unsigned f2s(float f) {
    unsigned u = __float_as_uint(f);
    return (u & 0x80000000u) ? ~u : (u | 0x80000000u);
}
__device__ __forceinline__ float s2f(unsigned u) {
    return __uint_as_float((u & 0x80000000u) ? (u & 0x7FFFFFFFu) : ~u);
}

// ---------------- K1 (256 blocks, plain launch, NO in-kernel device sync) --
// blocks 0..79:  per-class NMS — wave-ballot compaction of valid (s > 0.05)
//   -> rank-by-counting sort (keys unique: score desc, idx asc => exact
//   stable order) -> decode valid boxes -> bitmask NMS (MxM bit-matrix via
//   __ballot + register-only scan on wave 0; iterative fallback if matrix
//   exceeds LDS) -> push kept entries to global compact list.
// blocks 80..255: fill out (dets=0, cls_idx=r/1500+1, keep=0), disjoint
//   from everything the NMS blocks write — no ordering needed within K1.
// Kernel boundary provides the single device-scope release (R9 lesson:
// grid.sync() costs ~25 us on 8-XCD MI355X; kernel-boundary sync is free;
// R11 lesson: contiguous kept list keeps K2's walks latency-parallel).
__global__ __launch_bounds__(TPB) void nms_k1(
    const float* __restrict__ rois,    // (N,5)
    const float* __restrict__ deltas,  // (N, 4*81)
    const float* __restrict__ prob,    // (N, 81)
    const float* __restrict__ iminfo,  // (1,3)
    float4* __restrict__ keptBox,
    int*    __restrict__ keptRow,
    float*  __restrict__ keptScore,
    int*    __restrict__ ctrs,         // [0]=kept count (memset 0 by node)
    float*  __restrict__ out)
{
    const int tid  = threadIdx.x;
    const int lane = tid & 63;
    const int wv   = tid >> 6;
    const int b    = blockIdx.x;

    if (b >= FG) {
        // ---- fill blocks: dets=0, cls_idx, keep=0 (float4, grid-stride) ----
        const float4 z4 = make_float4(0.f, 0.f, 0.f, 0.f);
        const int stride = (K1_BLOCKS - FG) * TPB;
        int g = (b - FG) * TPB + tid;

        float4* dets4 = (float4*)out;                       // 180000
        for (int i = g; i < TOTAL * 6 / 4; i += stride) dets4[i] = z4;

        float4* cls4  = (float4*)(out + (size_t)TOTAL * 6); // 30000
        float4* keep4 = (float4*)(out + (size_t)TOTAL * 7);
        for (int i = g; i < TOTAL / 4; i += stride) {
            float fc = (float)((i * 4) / N_ROIS + 1);       // 1500%4==0
            cls4[i]  = make_float4(fc, fc, fc, fc);
            keep4[i] = z4;
        }
        return;
    }

    __shared__ unsigned long long key[MAXC];   // keys; later the mask matrix
    __shared__ unsigned long long skey[MAXC];  // rank-sorted keys
    __shared__ float4 box4[MAXC];
    __shared__ float  areaA[MAXC];
    __shared__ unsigned char keepf[MAXC], supp[MAXC];
    __shared__ int mcnt;

    const int c = b + 1;              // class 1..80
    const int cbase = b * N_ROIS;

    if (tid == 0) mcnt = 0;
    __syncthreads();

    // --- compaction: batch-load prob column, then wave-ballot compact ---
    float sv[NCHUNK];
    #pragma unroll
    for (int t = 0; t < NCHUNK; ++t) {
        int i = t * TPB + tid;
        sv[t] = (i < N_ROIS) ? prob[i * NUM_CLS + c] : 0.0f;
    }
    #pragma unroll
    for (int t = 0; t < NCHUNK; ++t) {
        int i = t * TPB + tid;
        bool val = (i < N_ROIS) && (sv[t] > SCORE_T);
        unsigned long long m = __ballot(val);
        int base = 0;
        if (lane == 0 && m) base = atomicAdd(&mcnt, __popcll(m));
        base = __shfl(base, 0, 64);
        if (val) {
            int pos = base + __popcll(m & ((1ull << lane) - 1ull));
            key[pos] = ((unsigned long long)(~f2s(sv[t])) << 32) | (unsigned)i;
        }
    }
    __syncthreads();
    const int M = mcnt;
    if (M == 0) return;

    // --- rank-by-counting sort: keys unique -> ranks are a permutation ---
    for (int i = tid; i < M; i += TPB) {
        unsigned long long kk = key[i];
        int cnt = 0;
        #pragma unroll 4
        for (int j = 0; j < M; ++j) cnt += (int)(key[j] < kk);
        skey[cnt] = kk;
    }
    __syncthreads();

    // --- decode boxes at sorted positions (match numpy op-for-op) ---
    const float Hm1 = iminfo[0] - 1.0f;
    const float Wm1 = iminfo[1] - 1.0f;
    for (int k = tid; k < M; k += TPB) {
        unsigned long long kk = skey[k];
        int i = (int)(kk & 0xFFFFFFFFu);
        const float* rp = rois + i * 5;
        float x1 = rp[1], y1 = rp[2], x2 = rp[3], y2 = rp[4];
        float w  = x2 - x1 + 1.0f;
        float h  = y2 - y1 + 1.0f;
        float cx = x1 + 0.5f * w;
        float cy = y1 + 0.5f * h;
        const float* dp = deltas + i * (4 * NUM_CLS) + c * 4;
        float dx = dp[0] / 10.0f, dy = dp[1] / 10.0f;
        float dw = dp[2] / 5.0f,  dh = dp[3] / 5.0f;
        float pcx = cx + w * dx;
        float pcy = cy + h * dy;
        float pw  = w * expf(dw);
        float ph  = h * expf(dh);
        float a1 = pcx - 0.5f * pw;
        float a2 = pcy - 0.5f * ph;
        float a3 = pcx + 0.5f * pw - 1.0f;
        float a4 = pcy + 0.5f * ph - 1.0f;
        a1 = fminf(fmaxf(a1, 0.0f), Wm1);
        a2 = fminf(fmaxf(a2, 0.0f), Hm1);
        a3 = fminf(fmaxf(a3, 0.0f), Wm1);
        a4 = fminf(fmaxf(a4, 0.0f), Hm1);
        box4[k]  = make_float4(a1, a2, a3, a4);
        areaA[k] = (a3 - a1 + 1.0f) * (a4 - a2 + 1.0f);
        keepf[k] = 0; supp[k] = 0;
    }
    __syncthreads();

    const int MW = (M + 63) >> 6;          // 64-bit words per mask row
    const bool fast = (M * MW <= MAXC);    // mask matrix fits in key[]

    if (fast) {
        // --- suppression bit-matrix: row r, bit j iff j>r && iou>0.5.
        //     Words w < r>>6 are identically zero: store 0, skip IoU. ---
        for (int r = wv; r < M; r += TPB / 64) {
            float4 br = box4[r];
            float  ar = areaA[r];
            const int w0 = r >> 6;
            if (lane == 0)
                for (int w = 0; w < w0; ++w) key[r * MW + w] = 0ull;
            for (int w = w0; w < MW; ++w) {
                int col = (w << 6) | lane;
                bool inb = (col < M);
                int j = inb ? col : 0;
                float4 bj = box4[j];
                float  aj = areaA[j];
                float iw = fminf(br.z, bj.z) - fmaxf(br.x, bj.x) + 1.0f;
                float ih = fminf(br.w, bj.w) - fmaxf(br.y, bj.y) + 1.0f;
                iw = fmaxf(iw, 0.0f);
                ih = fmaxf(ih, 0.0f);
                float inter = iw * ih;
                float iou = inter / ((ar + aj) - inter);
                bool pred = inb && (col > r) && (iou > NMS_T);
                unsigned long long mk = __ballot(pred);
                if (lane == 0) key[r * MW + w] = mk;
            }
        }
        __syncthreads();

        // --- serial scan, wave 0, prefetched register-only chain ---
        if (tid < 64) {
            const int lw = (tid < MW) ? tid : 0;
            unsigned long long acc = 0;        // suppressed bits, word `tid`
            unsigned long long mcur = key[lw]; // row 0
            for (int k = 0; k < M; ++k) {
                unsigned long long mnext =
                    (k + 1 < M) ? key[(k + 1) * MW + lw] : 0ull;
                int bit = (int)((acc >> (k & 63)) & 1ull);
                int sup = __shfl(bit, k >> 6, 64);
                if (!sup) {                    // wave-uniform branch
                    acc |= mcur;
                    if (tid == 0) keepf[k] = 1;
                }
                mcur = mnext;
            }
        }
        __syncthreads();
    } else {
        // --- fallback: iterative greedy NMS (correct for any M) ---
        for (int k = 0; k < M; ++k) {
            if (!supp[k]) {
                if (tid == 0) keepf[k] = 1;
                float4 bk = box4[k];
                float  ak = areaA[k];
                for (int j = k + 1 + tid; j < M; j += TPB) {
                    float4 bj = box4[j];
                    float  aj = areaA[j];
                    float iw = fminf(bk.z, bj.z) - fmaxf(bk.x, bj.x) + 1.0f;
                    float ih = fminf(bk.w, bj.w) - fmaxf(bk.y, bj.y) + 1.0f;
                    iw = fmaxf(iw, 0.0f);
                    ih = fmaxf(ih, 0.0f);
                    float inter = iw * ih;
                    float iou = inter / ((ak + aj) - inter);
                    if (iou > NMS_T) supp[j] = 1;
                }
            }
            __syncthreads();
        }
    }

    // --- push kept entries to global compact list ---
    for (int k = tid; k < M; k += TPB) {
        if (keepf[k]) {
            int p = atomicAdd(&ctrs[0], 1);
            keptRow[p]   = cbase + k;
            keptBox[p]   = box4[k];
            keptScore[p] = s2f(~(unsigned)(skey[k] >> 32));
        }
    }
}

// ---------------- K2 (1 block x 1024 threads): kth select + patch ----------
// Exact 100th-largest kept score via MSB-first radix-256 select (per-wave-
// group privatized histograms, parallel suffix-scan digit pick, LDS-
// compacted subset for rounds 2..4; tie-exact; global fallback if subset
// overflows LDS). Then the SAME block patches kept rows with s >= kth —
// no inter-kernel ordering needed, saving a dispatch.
__global__ __launch_bounds__(K2_TPB) void kth_patch_k2(
    const int*    __restrict__ ctrs,
    const int*    __restrict__ keptRow,
    const float4* __restrict__ keptBox,
    const float*  __restrict__ keptScore,
    float* __restrict__ out)
{
    __shared__ int hist4[4][256];     // 4 privatized copies (wave & 3)
    __shared__ unsigned sub[SUBCAP];  // 32 KB
    __shared__ int wtot[4];
    __shared__ unsigned s_d0, s_sp;
    __shared__ int s_kk, s_cnt;
    __shared__ float s_kth;

    const int tid  = threadIdx.x;
    const int lane = tid & 63;
    const int wv   = tid >> 6;        // 0..15
    const int hp   = wv & 3;          // histogram copy
    const int n = ctrs[0];

    if (n > MAX_DET) {
        // --- pass 1: top-8-digit histogram ---
        if (tid < 1024) {
            #pragma unroll
            for (int w = 0; w < 4; ++w) if (tid < 256) hist4[w][tid] = 0;
        }
        __syncthreads();
        for (int i = tid; i < n; i += K2_TPB)
            atomicAdd(&hist4[hp][f2s(keptScore[i]) >> 24], 1);
        __syncthreads();
        // digit pick: threads 0..255 own one bin each (waves 0..3)
        if (tid < 256) {
            const int h = hist4[0][tid] + hist4[1][tid] +
                          hist4[2][tid] + hist4[3][tid];
            int r = h;                          // wave suffix-scan (lane..63)
            #pragma unroll
            for (int off = 1; off < 64; off <<= 1) {
                int o = __shfl_down(r, off, 64);
                if (lane + off < 64) r += o;
            }
            if (lane == 0) wtot[wv] = r;
        }
        __syncthreads();
        if (tid < 256) {
            const int h = hist4[0][tid] + hist4[1][tid] +
                          hist4[2][tid] + hist4[3][tid];
            int r = h;
            #pragma unroll
            for (int off = 1; off < 64; off <<= 1) {
                int o = __shfl_down(r, off, 64);
                if (lane + off < 64) r += o;
            }
            int hi = 0;
            #pragma unroll
            for (int w2 = 0; w2 < 4; ++w2) if (w2 > wv) hi += wtot[w2];
            const int S_ge = r + hi, S_gt = S_ge - h;
            if (S_gt < MAX_DET && S_ge >= MAX_DET) {   // exactly one thread
                s_d0 = (unsigned)tid;
                s_kk = MAX_DET - S_gt;
            }
        }
        if (tid == 0) { s_cnt = 0; s_sp = 0u; }
        __syncthreads();
        const unsigned d0 = s_d0;

        // --- pass 2: compact lower-24 bits of matching subset into LDS ---
        for (int i0 = 0; i0 < n; i0 += K2_TPB) {
            int i = i0 + tid;
            unsigned u = (i < n) ? f2s(keptScore[i]) : 0u;
            bool match = (i < n) && ((u >> 24) == d0);
            unsigned long long m = __ballot(match);
            int base = 0;
            if (lane == 0 && m) base = atomicAdd(&s_cnt, __popcll(m));
            base = __shfl(base, 0, 64);
            if (match) {
                int pos = base + __popcll(m & ((1ull << lane) - 1ull));
                if (pos < SUBCAP) sub[pos] = u & 0xFFFFFFu;
            }
        }
        __syncthreads();
        const int ns = s_cnt;
        const bool inLds = (ns <= SUBCAP);
        const int limit = inLds ? ns : n;

        // --- rounds 1..3 over the 24 remaining bits ---
        for (int d = 1; d < 4; ++d) {
            const int shift = 24 - 8 * d;            // 16, 8, 0
            if (tid < 256) {
                #pragma unroll
                for (int w = 0; w < 4; ++w) hist4[w][tid] = 0;
            }
            __syncthreads();
            const unsigned sp = s_sp;
            for (int i = tid; i < limit; i += K2_TPB) {
                unsigned v; bool ok;
                if (inLds) { v = sub[i]; ok = true; }
                else {
                    unsigned u = f2s(keptScore[i]);
                    ok = ((u >> 24) == d0);
                    v = u & 0xFFFFFFu;
                }
                if (ok && (d == 1 || (v >> (shift + 8)) == sp))
                    atomicAdd(&hist4[hp][(v >> shift) & 255u], 1);
            }
            __syncthreads();
            if (tid < 256) {
                const int h = hist4[0][tid] + hist4[1][tid] +
                              hist4[2][tid] + hist4[3][tid];
                int r = h;
                #pragma unroll
                for (int off = 1; off < 64; off <<= 1) {
                    int o = __shfl_down(r, off, 64);
                    if (lane + off < 64) r += o;
                }
                if (lane == 0) wtot[wv] = r;
            }
            __syncthreads();
            if (tid < 256) {
                const int h = hist4[0][tid] + hist4[1][tid] +
                              hist4[2][tid] + hist4[3][tid];
                int r = h;
                #pragma unroll
                for (int off = 1; off < 64; off <<= 1) {
                    int o = __shfl_down(r, off, 64);
                    if (lane + off < 64) r += o;
                }
                int hi = 0;
                #pragma unroll
                for (int w2 = 0; w2 < 4; ++w2) if (w2 > wv) hi += wtot[w2];
                const int S_ge = r + hi, S_gt = S_ge - h;
                const int kk = s_kk;
                if (S_gt < kk && S_ge >= kk) {            // exactly one thread
                    s_sp = (s_sp << 8) | (unsigned)tid;
                    s_kk = kk - S_gt;
                }
            }
            __syncthreads();
        }
        if (tid == 0) s_kth = s2f((s_d0 << 24) | s_sp);
    } else {
        if (tid == 0) s_kth = -INFINITY;
    }
    __syncthreads();
    const float kth = s_kth;

    // --- patch kept rows (scattered fire-and-forget stores) ---
    for (int i = tid; i < n; i += K2_TPB) {
        float s = keptScore[i];
        if (s >= kth) {
            int r = keptRow[i];
            float4 b4 = keptBox[i];
            float* dst = out + (size_t)r * 6;
            dst[1] = b4.x; dst[2] = b4.y; dst[3] = b4.z; dst[4] = b4.w; dst[5] = s;
            out[(size_t)TOTAL * 7 + r] = 1.0f;
        }
    }
}

extern "C" void kernel_launch(void* const* d_in, const int* in_sizes, int n_in,
                              void* d_out, int out_size, void* d_ws, size_t ws_size,
                              hipStream_t stream) {
    const float* rois   = (const float*)d_in[0];  // (1500,5)
    const float* deltas = (const float*)d_in[1];  // (1500,324)
    const float* prob   = (const float*)d_in[2];  // (1500,81)
    const float* iminfo = (const float*)d_in[3];  // (1,3)
    float* out = (float*)d_out;

    // workspace: float4 first for 16B alignment
    float4* keptBox   = (float4*)d_ws;                 // TOTAL entries
    int*    keptRow   = (int*)(keptBox + TOTAL);       // TOTAL
    float*  keptScore = (float*)(keptRow + TOTAL);     // TOTAL
    int*    ctrs      = (int*)(keptScore + TOTAL);     // [kept] (+pad)

    hipMemsetAsync(ctrs, 0, sizeof(int), stream);
    nms_k1<<<K1_BLOCKS, TPB, 0, stream>>>(rois, deltas, prob, iminfo,
                                          keptBox, keptRow, keptScore, ctrs, out);
    kth_patch_k2<<<1, K2_TPB, 0, stream>>>(ctrs, keptRow, keptBox, keptScore, out);
}